// Round 3
// baseline (134.074 us; speedup 1.0000x reference)
//
#include <hip/hip_runtime.h>

#define BB 2048
#define DD 4096
#define PP 64
#define KK 64
#define EE 8
#define C2 128
#define NBLK BB        // 1 row per block; 4 waves = 4 channel-quarters (2 nt each)

typedef __attribute__((ext_vector_type(8))) short short8;
typedef __attribute__((ext_vector_type(4))) float floatx4;

__device__ inline unsigned pack2_trunc(float lo, float hi) { // 2 bf16 (truncate) in 1 u32
    unsigned ul = __builtin_bit_cast(unsigned, lo);
    unsigned uh = __builtin_bit_cast(unsigned, hi);
    return (uh & 0xFFFF0000u) | (ul >> 16);
}

// One row per BLOCK, 4 waves each owning 32 output channels (nt = 2w, 2w+1).
// All 4 waves load the full x row (same-CU L1 hits) + run the router redundantly
// (bit-identical instruction sequence => same e/gate; zero synchronization until the
// final 2-logit softmax). 2048 blocks -> 8 blocks/CU -> 32 waves/CU (max occupancy).
// Loss partials: wave 0 lanes 0..7 store d[] + argmax indicator straight from registers.
__global__ __launch_bounds__(256, 8) void moe_main(
    const float* __restrict__ x, const float* __restrict__ rw,
    const float* __restrict__ ew, const float* __restrict__ eb,
    float* __restrict__ out, float* __restrict__ ws)
{
    __shared__ float sh_h[4];                            // per-wave channel-quarter sums
    const int lane = threadIdx.x & 63;
    const int w = threadIdx.x >> 6;
    const int b = blockIdx.x;
    const int r = lane & 15, q = lane >> 4;
    const float* xb = x + (size_t)b * DD;

    // ---- load x in MFMA A-layout; fp32 col-sum partials; pack bf16 A-frags
    float ps[16];
    #pragma unroll
    for (int j = 0; j < 16; ++j) ps[j] = 0.f;
    short8 af[8];                                        // [mt*2+kb]
    #pragma unroll
    for (int mt = 0; mt < 4; ++mt) {
        #pragma unroll
        for (int kb = 0; kb < 2; ++kb) {
            const float* base = xb + (mt * 16 + r) * 64 + kb * 32 + q * 8;
            float4 v0 = *(const float4*)base;
            float4 v1 = *(const float4*)(base + 4);
            ps[kb*8+0] += v0.x; ps[kb*8+1] += v0.y; ps[kb*8+2] += v0.z; ps[kb*8+3] += v0.w;
            ps[kb*8+4] += v1.x; ps[kb*8+5] += v1.y; ps[kb*8+6] += v1.z; ps[kb*8+7] += v1.w;
            uint4 u;
            u.x = pack2_trunc(v0.x, v0.y); u.y = pack2_trunc(v0.z, v0.w);
            u.z = pack2_trunc(v1.x, v1.y); u.w = pack2_trunc(v1.z, v1.w);
            af[mt * 2 + kb] = __builtin_bit_cast(short8, u);
        }
    }

    // ---- router (fp32; strict first-max argmax matches np). Redundant across the 4 waves:
    // identical instruction sequence on identical data -> bit-identical d[], e, gate.
    float d[8];
    #pragma unroll
    for (int e2 = 0; e2 < 8; ++e2) {
        const float* rwe = rw + e2 * KK;
        float4 a0 = *(const float4*)(rwe + q * 8);
        float4 a1 = *(const float4*)(rwe + q * 8 + 4);
        float4 b0 = *(const float4*)(rwe + 32 + q * 8);
        float4 b1 = *(const float4*)(rwe + 32 + q * 8 + 4);
        float t = ps[0]*a0.x + ps[1]*a0.y + ps[2]*a0.z + ps[3]*a0.w
                + ps[4]*a1.x + ps[5]*a1.y + ps[6]*a1.z + ps[7]*a1.w
                + ps[8]*b0.x + ps[9]*b0.y + ps[10]*b0.z + ps[11]*b0.w
                + ps[12]*b1.x + ps[13]*b1.y + ps[14]*b1.z + ps[15]*b1.w;
        t += __shfl_xor(t, 1);  t += __shfl_xor(t, 2);  t += __shfl_xor(t, 4);
        t += __shfl_xor(t, 8);  t += __shfl_xor(t, 16); t += __shfl_xor(t, 32);
        d[e2] = t;                                       // all lanes hold it
    }
    float gate = d[0]; int e = 0;
    #pragma unroll
    for (int e2 = 1; e2 < 8; ++e2)
        if (d[e2] > gate) { gate = d[e2]; e = e2; }

    // ---- outputs that only need router results: wave 0, lanes 0..7, straight from registers
    if (w == 0 && lane < 8) {
        float on = (gate != 0.f) ? 1.f : 0.f;
        out[BB * 2 + b * 8 + lane] = (lane == e) ? on : 0.f;   // select0 (one-hot row)
        ws[b * 16 + lane]     = d[lane];                       // loss partial: select value
        ws[b * 16 + 8 + lane] = (lane == e) ? 1.f : 0.f;       // loss partial: argmax indicator
    }

    // ---- expert compute (this wave's 32 channels): inline fp32->bf16 B-frags, mfma, (z+bias)^3
    const float* we = ew + (size_t)e * (C2 * KK);
    float h = 0.f;
    #pragma unroll
    for (int ntl = 0; ntl < 2; ++ntl) {
        const int nt = w * 2 + ntl;
        float bs = eb[e * C2 + nt * 16 + r];             // c = nt*16 + (lane&15)
        const float* wr = we + (nt * 16 + r) * KK + q * 8;
        float4 w0 = *(const float4*)wr;
        float4 w1 = *(const float4*)(wr + 4);
        float4 w2 = *(const float4*)(wr + 32);
        float4 w3 = *(const float4*)(wr + 36);
        uint4 u0, u1;
        u0.x = pack2_trunc(w0.x, w0.y); u0.y = pack2_trunc(w0.z, w0.w);
        u0.z = pack2_trunc(w1.x, w1.y); u0.w = pack2_trunc(w1.z, w1.w);
        u1.x = pack2_trunc(w2.x, w2.y); u1.y = pack2_trunc(w2.z, w2.w);
        u1.z = pack2_trunc(w3.x, w3.y); u1.w = pack2_trunc(w3.z, w3.w);
        short8 bf0 = __builtin_bit_cast(short8, u0);
        short8 bf1 = __builtin_bit_cast(short8, u1);
        #pragma unroll
        for (int mt = 0; mt < 4; ++mt) {
            floatx4 a4 = (floatx4){0.f, 0.f, 0.f, 0.f};
            a4 = __builtin_amdgcn_mfma_f32_16x16x32_bf16(af[mt*2+0], bf0, a4, 0, 0, 0);
            a4 = __builtin_amdgcn_mfma_f32_16x16x32_bf16(af[mt*2+1], bf1, a4, 0, 0, 0);
            #pragma unroll
            for (int i = 0; i < 4; ++i) {
                float z = a4[i] + bs;
                h = fmaf(z * z, z, h);
            }
        }
    }
    #pragma unroll
    for (int off = 1; off < 64; off <<= 1)
        h += __shfl_xor(h, off);

    if (lane == 0) sh_h[w] = h;
    __syncthreads();

    if (threadIdx.x == 0) {
        float l0 = gate * (sh_h[0] + sh_h[1]);           // channels 0..63
        float l1 = gate * (sh_h[2] + sh_h[3]);           // channels 64..127
        float m = fmaxf(l0, l1);
        float e0 = __expf(l0 - m), e1 = __expf(l1 - m);
        float inv = 1.f / (e0 + e1);
        float2 o; o.x = e0 * inv; o.y = e1 * inv;
        *(float2*)(out + b * 2) = o;
    }
}

// Stage 2: reduce 2048 row-partials (16 floats each) -> loss. One block, 128 KB read.
__global__ __launch_bounds__(256) void loss2(
    const float* __restrict__ ws, float* __restrict__ out)
{
    __shared__ float red[4][16];
    const int t = threadIdx.x;
    const int w = t >> 6, lane = t & 63;

    float p[8] = {0,0,0,0,0,0,0,0};
    float c[8] = {0,0,0,0,0,0,0,0};
    #pragma unroll
    for (int it = 0; it < BB / 256; ++it) {              // 8 iterations
        const float4* row = (const float4*)(ws + (size_t)(it * 256 + t) * 16);
        float4 r0 = row[0], r1 = row[1], r2 = row[2], r3 = row[3];
        p[0] += r0.x; p[1] += r0.y; p[2] += r0.z; p[3] += r0.w;
        p[4] += r1.x; p[5] += r1.y; p[6] += r1.z; p[7] += r1.w;
        c[0] += r2.x; c[1] += r2.y; c[2] += r2.z; c[3] += r2.w;
        c[4] += r3.x; c[5] += r3.y; c[6] += r3.z; c[7] += r3.w;
    }
    #pragma unroll
    for (int off = 32; off > 0; off >>= 1) {
        #pragma unroll
        for (int e2 = 0; e2 < 8; ++e2) {
            p[e2] += __shfl_xor(p[e2], off);
            c[e2] += __shfl_xor(c[e2], off);
        }
    }
    if (lane == 0) {
        #pragma unroll
        for (int e2 = 0; e2 < 8; ++e2) { red[w][e2] = p[e2]; red[w][8 + e2] = c[e2]; }
    }
    __syncthreads();
    if (t == 0) {
        float loss = 0.f;
        #pragma unroll
        for (int e2 = 0; e2 < 8; ++e2) {
            float sp = red[0][e2] + red[1][e2] + red[2][e2] + red[3][e2];
            float sc = red[0][8 + e2] + red[1][8 + e2] + red[2][8 + e2] + red[3][8 + e2];
            loss += (sp * (1.f / BB)) * (sc * (1.f / BB));
        }
        out[BB * 2 + BB * 8] = loss * (float)EE;
    }
}

extern "C" void kernel_launch(void* const* d_in, const int* in_sizes, int n_in,
                              void* d_out, int out_size, void* d_ws, size_t ws_size,
                              hipStream_t stream) {
    (void)in_sizes; (void)n_in; (void)out_size; (void)ws_size;
    const float* x  = (const float*)d_in[0];
    const float* rw = (const float*)d_in[1];
    const float* ew = (const float*)d_in[2];
    const float* eb = (const float*)d_in[3];
    float* out = (float*)d_out;
    float* ws  = (float*)d_ws;                           // 2048*16 floats of row partials (no init)

    moe_main<<<NBLK, 256, 0, stream>>>(x, rw, ew, eb, out, ws);
    loss2<<<1, 256, 0, stream>>>(ws, out);
}

// Round 4
// 108.437 us; speedup vs baseline: 1.2364x; 1.2364x over previous
//
#include <hip/hip_runtime.h>

#define BB 2048
#define DD 4096
#define PP 64
#define KK 64
#define EE 8
#define C2 128
#define NBLK BB        // 1 row per block; 4 waves = 4 channel-quarters (2 nt each)

typedef __attribute__((ext_vector_type(8))) short short8;
typedef __attribute__((ext_vector_type(4))) float floatx4;

__device__ inline unsigned pack2_trunc(float lo, float hi) { // 2 bf16 (truncate) in 1 u32
    unsigned ul = __builtin_bit_cast(unsigned, lo);
    unsigned uh = __builtin_bit_cast(unsigned, hi);
    return (uh & 0xFFFF0000u) | (ul >> 16);
}

// One row per BLOCK, 4 waves each owning 32 output channels (nt = 2w, 2w+1).
// All 4 waves load the full x row (same-CU L1 hits) + run the router redundantly
// (bit-identical instruction sequence => same e/gate; zero synchronization until the
// final 2-logit softmax). 2048 blocks.
// NOTE: plain __launch_bounds__(256) — round 3 showed that forcing 8 waves/EU (64-VGPR cap)
// makes the compiler spill ~145 B/thread (WRITE_SIZE 0.15->76 MB, moe 60 us). Body needs ~60
// VGPRs; let the allocator pick and take whatever occupancy that allows.
__global__ __launch_bounds__(256) void moe_main(
    const float* __restrict__ x, const float* __restrict__ rw,
    const float* __restrict__ ew, const float* __restrict__ eb,
    float* __restrict__ out, float* __restrict__ ws)
{
    __shared__ float sh_h[4];                            // per-wave channel-quarter sums
    const int lane = threadIdx.x & 63;
    const int w = threadIdx.x >> 6;
    const int b = blockIdx.x;
    const int r = lane & 15, q = lane >> 4;
    const float* xb = x + (size_t)b * DD;

    // ---- load x in MFMA A-layout; fp32 col-sum partials; pack bf16 A-frags
    float ps[16];
    #pragma unroll
    for (int j = 0; j < 16; ++j) ps[j] = 0.f;
    short8 af[8];                                        // [mt*2+kb]
    #pragma unroll
    for (int mt = 0; mt < 4; ++mt) {
        #pragma unroll
        for (int kb = 0; kb < 2; ++kb) {
            const float* base = xb + (mt * 16 + r) * 64 + kb * 32 + q * 8;
            float4 v0 = *(const float4*)base;
            float4 v1 = *(const float4*)(base + 4);
            ps[kb*8+0] += v0.x; ps[kb*8+1] += v0.y; ps[kb*8+2] += v0.z; ps[kb*8+3] += v0.w;
            ps[kb*8+4] += v1.x; ps[kb*8+5] += v1.y; ps[kb*8+6] += v1.z; ps[kb*8+7] += v1.w;
            uint4 u;
            u.x = pack2_trunc(v0.x, v0.y); u.y = pack2_trunc(v0.z, v0.w);
            u.z = pack2_trunc(v1.x, v1.y); u.w = pack2_trunc(v1.z, v1.w);
            af[mt * 2 + kb] = __builtin_bit_cast(short8, u);
        }
    }

    // ---- router (fp32; strict first-max argmax matches np). Redundant across the 4 waves:
    // identical instruction sequence on identical data -> bit-identical d[], e, gate.
    float d[8];
    #pragma unroll
    for (int e2 = 0; e2 < 8; ++e2) {
        const float* rwe = rw + e2 * KK;
        float4 a0 = *(const float4*)(rwe + q * 8);
        float4 a1 = *(const float4*)(rwe + q * 8 + 4);
        float4 b0 = *(const float4*)(rwe + 32 + q * 8);
        float4 b1 = *(const float4*)(rwe + 32 + q * 8 + 4);
        float t = ps[0]*a0.x + ps[1]*a0.y + ps[2]*a0.z + ps[3]*a0.w
                + ps[4]*a1.x + ps[5]*a1.y + ps[6]*a1.z + ps[7]*a1.w
                + ps[8]*b0.x + ps[9]*b0.y + ps[10]*b0.z + ps[11]*b0.w
                + ps[12]*b1.x + ps[13]*b1.y + ps[14]*b1.z + ps[15]*b1.w;
        t += __shfl_xor(t, 1);  t += __shfl_xor(t, 2);  t += __shfl_xor(t, 4);
        t += __shfl_xor(t, 8);  t += __shfl_xor(t, 16); t += __shfl_xor(t, 32);
        d[e2] = t;                                       // all lanes hold it
    }
    float gate = d[0]; int e = 0;
    #pragma unroll
    for (int e2 = 1; e2 < 8; ++e2)
        if (d[e2] > gate) { gate = d[e2]; e = e2; }

    // ---- outputs that only need router results: wave 0, lanes 0..7, straight from registers
    if (w == 0 && lane < 8) {
        float on = (gate != 0.f) ? 1.f : 0.f;
        out[BB * 2 + b * 8 + lane] = (lane == e) ? on : 0.f;   // select0 (one-hot row)
        ws[b * 16 + lane]     = d[lane];                       // loss partial: select value
        ws[b * 16 + 8 + lane] = (lane == e) ? 1.f : 0.f;       // loss partial: argmax indicator
    }

    // ---- expert compute (this wave's 32 channels): inline fp32->bf16 B-frags, mfma, (z+bias)^3
    const float* we = ew + (size_t)e * (C2 * KK);
    float h = 0.f;
    #pragma unroll
    for (int ntl = 0; ntl < 2; ++ntl) {
        const int nt = w * 2 + ntl;
        float bs = eb[e * C2 + nt * 16 + r];             // c = nt*16 + (lane&15)
        const float* wr = we + (nt * 16 + r) * KK + q * 8;
        float4 w0 = *(const float4*)wr;
        float4 w1 = *(const float4*)(wr + 4);
        float4 w2 = *(const float4*)(wr + 32);
        float4 w3 = *(const float4*)(wr + 36);
        uint4 u0, u1;
        u0.x = pack2_trunc(w0.x, w0.y); u0.y = pack2_trunc(w0.z, w0.w);
        u0.z = pack2_trunc(w1.x, w1.y); u0.w = pack2_trunc(w1.z, w1.w);
        u1.x = pack2_trunc(w2.x, w2.y); u1.y = pack2_trunc(w2.z, w2.w);
        u1.z = pack2_trunc(w3.x, w3.y); u1.w = pack2_trunc(w3.z, w3.w);
        short8 bf0 = __builtin_bit_cast(short8, u0);
        short8 bf1 = __builtin_bit_cast(short8, u1);
        #pragma unroll
        for (int mt = 0; mt < 4; ++mt) {
            floatx4 a4 = (floatx4){0.f, 0.f, 0.f, 0.f};
            a4 = __builtin_amdgcn_mfma_f32_16x16x32_bf16(af[mt*2+0], bf0, a4, 0, 0, 0);
            a4 = __builtin_amdgcn_mfma_f32_16x16x32_bf16(af[mt*2+1], bf1, a4, 0, 0, 0);
            #pragma unroll
            for (int i = 0; i < 4; ++i) {
                float z = a4[i] + bs;
                h = fmaf(z * z, z, h);
            }
        }
    }
    #pragma unroll
    for (int off = 1; off < 64; off <<= 1)
        h += __shfl_xor(h, off);

    if (lane == 0) sh_h[w] = h;
    __syncthreads();

    if (threadIdx.x == 0) {
        float l0 = gate * (sh_h[0] + sh_h[1]);           // channels 0..63
        float l1 = gate * (sh_h[2] + sh_h[3]);           // channels 64..127
        float m = fmaxf(l0, l1);
        float e0 = __expf(l0 - m), e1 = __expf(l1 - m);
        float inv = 1.f / (e0 + e1);
        float2 o; o.x = e0 * inv; o.y = e1 * inv;
        *(float2*)(out + b * 2) = o;
    }
}

// Stage 2: reduce 2048 row-partials (16 floats each) -> loss. One block, 128 KB read.
__global__ __launch_bounds__(256) void loss2(
    const float* __restrict__ ws, float* __restrict__ out)
{
    __shared__ float red[4][16];
    const int t = threadIdx.x;
    const int w = t >> 6, lane = t & 63;

    float p[8] = {0,0,0,0,0,0,0,0};
    float c[8] = {0,0,0,0,0,0,0,0};
    #pragma unroll
    for (int it = 0; it < BB / 256; ++it) {              // 8 iterations
        const float4* row = (const float4*)(ws + (size_t)(it * 256 + t) * 16);
        float4 r0 = row[0], r1 = row[1], r2 = row[2], r3 = row[3];
        p[0] += r0.x; p[1] += r0.y; p[2] += r0.z; p[3] += r0.w;
        p[4] += r1.x; p[5] += r1.y; p[6] += r1.z; p[7] += r1.w;
        c[0] += r2.x; c[1] += r2.y; c[2] += r2.z; c[3] += r2.w;
        c[4] += r3.x; c[5] += r3.y; c[6] += r3.z; c[7] += r3.w;
    }
    #pragma unroll
    for (int off = 32; off > 0; off >>= 1) {
        #pragma unroll
        for (int e2 = 0; e2 < 8; ++e2) {
            p[e2] += __shfl_xor(p[e2], off);
            c[e2] += __shfl_xor(c[e2], off);
        }
    }
    if (lane == 0) {
        #pragma unroll
        for (int e2 = 0; e2 < 8; ++e2) { red[w][e2] = p[e2]; red[w][8 + e2] = c[e2]; }
    }
    __syncthreads();
    if (t == 0) {
        float loss = 0.f;
        #pragma unroll
        for (int e2 = 0; e2 < 8; ++e2) {
            float sp = red[0][e2] + red[1][e2] + red[2][e2] + red[3][e2];
            float sc = red[0][8 + e2] + red[1][8 + e2] + red[2][8 + e2] + red[3][8 + e2];
            loss += (sp * (1.f / BB)) * (sc * (1.f / BB));
        }
        out[BB * 2 + BB * 8] = loss * (float)EE;
    }
}

extern "C" void kernel_launch(void* const* d_in, const int* in_sizes, int n_in,
                              void* d_out, int out_size, void* d_ws, size_t ws_size,
                              hipStream_t stream) {
    (void)in_sizes; (void)n_in; (void)out_size; (void)ws_size;
    const float* x  = (const float*)d_in[0];
    const float* rw = (const float*)d_in[1];
    const float* ew = (const float*)d_in[2];
    const float* eb = (const float*)d_in[3];
    float* out = (float*)d_out;
    float* ws  = (float*)d_ws;                           // 2048*16 floats of row partials (no init)

    moe_main<<<NBLK, 256, 0, stream>>>(x, rw, ew, eb, out, ws);
    loss2<<<1, 256, 0, stream>>>(ws, out);
}

// Round 5
// 98.844 us; speedup vs baseline: 1.3564x; 1.0970x over previous
//
#include <hip/hip_runtime.h>

#define BB 2048
#define DD 4096
#define PP 64
#define KK 64
#define EE 8
#define C2 128
#define NBLK BB        // 1 row per block; 4 waves = 4 channel-quarters (2 nt each)

typedef __attribute__((ext_vector_type(8))) short short8;
typedef __attribute__((ext_vector_type(4))) float floatx4;

__device__ inline unsigned pack2_trunc(float lo, float hi) { // 2 bf16 (truncate) in 1 u32
    unsigned ul = __builtin_bit_cast(unsigned, lo);
    unsigned uh = __builtin_bit_cast(unsigned, hi);
    return (uh & 0xFFFF0000u) | (ul >> 16);
}

// async global->LDS, 16B per lane, zero VGPR destination cost.
// LDS dest = wave-uniform base + lane*16 (HW semantic); global src is per-lane.
__device__ inline void gload16(const float* src, float* lds_dst_uniform) {
    __builtin_amdgcn_global_load_lds(
        (const __attribute__((address_space(1))) unsigned int*)src,
        (__attribute__((address_space(3))) unsigned int*)lds_dst_uniform, 16, 0, 0);
}

// One row per BLOCK, 4 waves each owning 32 output channels (nt = 2w, 2w+1).
// R4 forensics: the harness's 256 MB poison-fill flushes L3 every iteration, so x is
// HBM-COLD; per-wave float4 loads were MLP-starved (~390 GB/s, R1 counters). Fix:
// stage the 16 KB row via global_load_lds (no VGPR cost -> full row in flight at once),
// share it across all 4 waves, XOR-swizzle (pre-swizzled GLOBAL src + swizzled LDS read,
// granule ^= row&7) so column-slice ds_read_b128s hit all 32 banks.
// Values read are bit-identical to the direct-load version -> router/argmax unchanged.
__global__ __launch_bounds__(256) void moe_main(
    const float* __restrict__ x, const float* __restrict__ rw,
    const float* __restrict__ ew, const float* __restrict__ eb,
    float* __restrict__ out, float* __restrict__ ws)
{
    __shared__ float xs[64 * 64];                        // 16 KB: x row, [patch][k], swizzled
    __shared__ float sh_h[4];                            // per-wave channel-quarter sums
    const int lane = threadIdx.x & 63;
    const int w = threadIdx.x >> 6;
    const int b = blockIdx.x;
    const int r = lane & 15, q = lane >> 4;
    const float* xb = x + (size_t)b * DD;

    // ---- stage x row into LDS (16 x 1KB issues, 4 per wave), swizzled at the source:
    // LDS[row][G] = global[row][G ^ (row&7)]  (G = 16B granule index 0..15 within a row)
    #pragma unroll
    for (int j = 0; j < 4; ++j) {
        const int row = (w * 4 + j) * 4 + (lane >> 4);   // this lane's global row
        const int g   = (lane & 15) ^ (row & 7);         // pre-swizzled source granule
        gload16(xb + row * 64 + g * 4, &xs[(w * 4 + j) * 256]);  // dst uniform per wave
    }
    __syncthreads();                                     // compiler drains vmcnt(0) before barrier

    // ---- read x from LDS in MFMA A-layout; fp32 col-sum partials; pack bf16 A-frags
    const int s = r & 7;                                 // read-side XOR key: (mt*16+r)&7 == r&7
    float ps[16];
    #pragma unroll
    for (int j = 0; j < 16; ++j) ps[j] = 0.f;
    short8 af[8];                                        // [mt*2+kb]
    #pragma unroll
    for (int mt = 0; mt < 4; ++mt) {
        #pragma unroll
        for (int kb = 0; kb < 2; ++kb) {
            const float* base = &xs[(mt * 16 + r) * 64 + kb * 32];
            float4 v0 = *(const float4*)(base + (((q * 2 + 0) ^ s) << 2));
            float4 v1 = *(const float4*)(base + (((q * 2 + 1) ^ s) << 2));
            ps[kb*8+0] += v0.x; ps[kb*8+1] += v0.y; ps[kb*8+2] += v0.z; ps[kb*8+3] += v0.w;
            ps[kb*8+4] += v1.x; ps[kb*8+5] += v1.y; ps[kb*8+6] += v1.z; ps[kb*8+7] += v1.w;
            uint4 u;
            u.x = pack2_trunc(v0.x, v0.y); u.y = pack2_trunc(v0.z, v0.w);
            u.z = pack2_trunc(v1.x, v1.y); u.w = pack2_trunc(v1.z, v1.w);
            af[mt * 2 + kb] = __builtin_bit_cast(short8, u);
        }
    }

    // ---- router (fp32; strict first-max argmax matches np). Redundant across the 4 waves:
    // identical instruction sequence on identical data -> bit-identical d[], e, gate.
    float d[8];
    #pragma unroll
    for (int e2 = 0; e2 < 8; ++e2) {
        const float* rwe = rw + e2 * KK;
        float4 a0 = *(const float4*)(rwe + q * 8);
        float4 a1 = *(const float4*)(rwe + q * 8 + 4);
        float4 b0 = *(const float4*)(rwe + 32 + q * 8);
        float4 b1 = *(const float4*)(rwe + 32 + q * 8 + 4);
        float t = ps[0]*a0.x + ps[1]*a0.y + ps[2]*a0.z + ps[3]*a0.w
                + ps[4]*a1.x + ps[5]*a1.y + ps[6]*a1.z + ps[7]*a1.w
                + ps[8]*b0.x + ps[9]*b0.y + ps[10]*b0.z + ps[11]*b0.w
                + ps[12]*b1.x + ps[13]*b1.y + ps[14]*b1.z + ps[15]*b1.w;
        t += __shfl_xor(t, 1);  t += __shfl_xor(t, 2);  t += __shfl_xor(t, 4);
        t += __shfl_xor(t, 8);  t += __shfl_xor(t, 16); t += __shfl_xor(t, 32);
        d[e2] = t;                                       // all lanes hold it
    }
    float gate = d[0]; int e = 0;
    #pragma unroll
    for (int e2 = 1; e2 < 8; ++e2)
        if (d[e2] > gate) { gate = d[e2]; e = e2; }

    // ---- outputs that only need router results: wave 0, lanes 0..7, straight from registers
    if (w == 0 && lane < 8) {
        float on = (gate != 0.f) ? 1.f : 0.f;
        out[BB * 2 + b * 8 + lane] = (lane == e) ? on : 0.f;   // select0 (one-hot row)
        ws[b * 16 + lane]     = d[lane];                       // loss partial: select value
        ws[b * 16 + 8 + lane] = (lane == e) ? 1.f : 0.f;       // loss partial: argmax indicator
    }

    // ---- expert compute (this wave's 32 channels): inline fp32->bf16 B-frags, mfma, (z+bias)^3
    const float* we = ew + (size_t)e * (C2 * KK);
    float h = 0.f;
    #pragma unroll
    for (int ntl = 0; ntl < 2; ++ntl) {
        const int nt = w * 2 + ntl;
        float bs = eb[e * C2 + nt * 16 + r];             // c = nt*16 + (lane&15)
        const float* wr = we + (nt * 16 + r) * KK + q * 8;
        float4 w0 = *(const float4*)wr;
        float4 w1 = *(const float4*)(wr + 4);
        float4 w2 = *(const float4*)(wr + 32);
        float4 w3 = *(const float4*)(wr + 36);
        uint4 u0, u1;
        u0.x = pack2_trunc(w0.x, w0.y); u0.y = pack2_trunc(w0.z, w0.w);
        u0.z = pack2_trunc(w1.x, w1.y); u0.w = pack2_trunc(w1.z, w1.w);
        u1.x = pack2_trunc(w2.x, w2.y); u1.y = pack2_trunc(w2.z, w2.w);
        u1.z = pack2_trunc(w3.x, w3.y); u1.w = pack2_trunc(w3.z, w3.w);
        short8 bf0 = __builtin_bit_cast(short8, u0);
        short8 bf1 = __builtin_bit_cast(short8, u1);
        #pragma unroll
        for (int mt = 0; mt < 4; ++mt) {
            floatx4 a4 = (floatx4){0.f, 0.f, 0.f, 0.f};
            a4 = __builtin_amdgcn_mfma_f32_16x16x32_bf16(af[mt*2+0], bf0, a4, 0, 0, 0);
            a4 = __builtin_amdgcn_mfma_f32_16x16x32_bf16(af[mt*2+1], bf1, a4, 0, 0, 0);
            #pragma unroll
            for (int i = 0; i < 4; ++i) {
                float z = a4[i] + bs;
                h = fmaf(z * z, z, h);
            }
        }
    }
    #pragma unroll
    for (int off = 1; off < 64; off <<= 1)
        h += __shfl_xor(h, off);

    if (lane == 0) sh_h[w] = h;
    __syncthreads();

    if (threadIdx.x == 0) {
        float l0 = gate * (sh_h[0] + sh_h[1]);           // channels 0..63
        float l1 = gate * (sh_h[2] + sh_h[3]);           // channels 64..127
        float m = fmaxf(l0, l1);
        float e0 = __expf(l0 - m), e1 = __expf(l1 - m);
        float inv = 1.f / (e0 + e1);
        float2 o; o.x = e0 * inv; o.y = e1 * inv;
        *(float2*)(out + b * 2) = o;
    }
}

// Stage 2: reduce 2048 row-partials (16 floats each) -> loss. One block, 128 KB read.
__global__ __launch_bounds__(256) void loss2(
    const float* __restrict__ ws, float* __restrict__ out)
{
    __shared__ float red[4][16];
    const int t = threadIdx.x;
    const int w = t >> 6, lane = t & 63;

    float p[8] = {0,0,0,0,0,0,0,0};
    float c[8] = {0,0,0,0,0,0,0,0};
    #pragma unroll
    for (int it = 0; it < BB / 256; ++it) {              // 8 iterations
        const float4* row = (const float4*)(ws + (size_t)(it * 256 + t) * 16);
        float4 r0 = row[0], r1 = row[1], r2 = row[2], r3 = row[3];
        p[0] += r0.x; p[1] += r0.y; p[2] += r0.z; p[3] += r0.w;
        p[4] += r1.x; p[5] += r1.y; p[6] += r1.z; p[7] += r1.w;
        c[0] += r2.x; c[1] += r2.y; c[2] += r2.z; c[3] += r2.w;
        c[4] += r3.x; c[5] += r3.y; c[6] += r3.z; c[7] += r3.w;
    }
    #pragma unroll
    for (int off = 32; off > 0; off >>= 1) {
        #pragma unroll
        for (int e2 = 0; e2 < 8; ++e2) {
            p[e2] += __shfl_xor(p[e2], off);
            c[e2] += __shfl_xor(c[e2], off);
        }
    }
    if (lane == 0) {
        #pragma unroll
        for (int e2 = 0; e2 < 8; ++e2) { red[w][e2] = p[e2]; red[w][8 + e2] = c[e2]; }
    }
    __syncthreads();
    if (t == 0) {
        float loss = 0.f;
        #pragma unroll
        for (int e2 = 0; e2 < 8; ++e2) {
            float sp = red[0][e2] + red[1][e2] + red[2][e2] + red[3][e2];
            float sc = red[0][8 + e2] + red[1][8 + e2] + red[2][8 + e2] + red[3][8 + e2];
            loss += (sp * (1.f / BB)) * (sc * (1.f / BB));
        }
        out[BB * 2 + BB * 8] = loss * (float)EE;
    }
}

extern "C" void kernel_launch(void* const* d_in, const int* in_sizes, int n_in,
                              void* d_out, int out_size, void* d_ws, size_t ws_size,
                              hipStream_t stream) {
    (void)in_sizes; (void)n_in; (void)out_size; (void)ws_size;
    const float* x  = (const float*)d_in[0];
    const float* rw = (const float*)d_in[1];
    const float* ew = (const float*)d_in[2];
    const float* eb = (const float*)d_in[3];
    float* out = (float*)d_out;
    float* ws  = (float*)d_ws;                           // 2048*16 floats of row partials (no init)

    moe_main<<<NBLK, 256, 0, stream>>>(x, rw, ew, eb, out, ws);
    loss2<<<1, 256, 0, stream>>>(ws, out);
}